// Round 1
// baseline (3645.094 us; speedup 1.0000x reference)
//
#include <hip/hip_runtime.h>
#include <math.h>

// Problem constants (TransformerEncoder, Transformer-XL style)
#define NL 4
#define DM 1024
#define NH 8
#define HD 128
#define BB 8
#define LL 512
#define MM (BB*LL)      // 4096 rows
#define PEN (2*LL)      // 1024 pe rows
#define QB 16           // query tile
#define KB 32           // key tile

// Workspace layout (floats):
//   pe   [PEN][HD]            131072
//   d2   [NH][PEN]              8192
//   qv   [MM][2*DM]          8388608
//   tmp  [MM][DM]            4194304
// total 12,722,176 f32 = 48.53 MiB  (ws_size must cover this)

// ---------------- relative position embedding ----------------
__global__ __launch_bounds__(256) void pe_kernel(float* __restrict__ pe) {
  int idx = blockIdx.x * 256 + threadIdx.x;
  if (idx >= PEN * HD) return;
  int p = idx / HD, j = idx % HD;
  int tt = (j < 64) ? j : (j - 64);
  // inv_freq = exp(t * (-ln(10000)/63))  (half-1 = 63 per reference!)
  float invf = expf((float)tt * (-9.210340371976184f / 63.0f));
  float ang = (float)(p - LL) * invf;
  pe[idx] = (j < 64) ? sinf(ang) : cosf(ang);
}

// ---------------- d2[n][p] = (rw[n]-rr[n]) . pe[p] ----------------
__global__ __launch_bounds__(256) void d2_kernel(const float* __restrict__ rrb,
                                                 const float* __restrict__ rwb,
                                                 const float* __restrict__ pe,
                                                 float* __restrict__ d2) {
  int idx = blockIdx.x * 256 + threadIdx.x;
  if (idx >= NH * PEN) return;
  int n = idx / PEN, p = idx % PEN;
  float s = 0.f;
  for (int d = 0; d < HD; ++d)
    s += (rwb[n*HD + d] - rrb[n*HD + d]) * pe[p*HD + d];
  d2[idx] = s;
}

// ---------------- f32 GEMM: C[M][N] = A[M][K] @ Bw[N][K]^T (+bias,relu) ----
// 64x64 tile, BK=16, 256 threads, 4x4 per-thread micro-tile.
template<bool BIAS, bool RELU>
__global__ __launch_bounds__(256) void gemm_nt(const float* __restrict__ A,
                                               const float* __restrict__ Bw,
                                               const float* __restrict__ bias,
                                               float* __restrict__ C,
                                               int M, int N, int K) {
  __shared__ float As[16][68];   // [k][m], pad->float4-aligned rows (68*4=272B)
  __shared__ float Bs[16][68];   // [k][n]
  const int t = threadIdx.x;
  const int bm = blockIdx.y * 64;
  const int bn = blockIdx.x * 64;
  const int lr = t >> 2;         // 0..63 tile row for loads
  const int lc = (t & 3) * 4;    // k offset for loads
  const int tm = (t >> 4) * 4;   // 0..60 output rows
  const int tn = (t & 15) * 4;   // 0..60 output cols
  float acc[4][4] = {};
  const float* Ap = A + (size_t)(bm + lr) * K + lc;
  const float* Bp = Bw + (size_t)(bn + lr) * K + lc;
  for (int k0 = 0; k0 < K; k0 += 16) {
    float4 av = *(const float4*)(Ap + k0);
    float4 bv = *(const float4*)(Bp + k0);
    As[lc+0][lr] = av.x; As[lc+1][lr] = av.y; As[lc+2][lr] = av.z; As[lc+3][lr] = av.w;
    Bs[lc+0][lr] = bv.x; Bs[lc+1][lr] = bv.y; Bs[lc+2][lr] = bv.z; Bs[lc+3][lr] = bv.w;
    __syncthreads();
#pragma unroll
    for (int kk = 0; kk < 16; ++kk) {
      float4 a  = *(const float4*)&As[kk][tm];
      float4 bq = *(const float4*)&Bs[kk][tn];
      acc[0][0] += a.x*bq.x; acc[0][1] += a.x*bq.y; acc[0][2] += a.x*bq.z; acc[0][3] += a.x*bq.w;
      acc[1][0] += a.y*bq.x; acc[1][1] += a.y*bq.y; acc[1][2] += a.y*bq.z; acc[1][3] += a.y*bq.w;
      acc[2][0] += a.z*bq.x; acc[2][1] += a.z*bq.y; acc[2][2] += a.z*bq.z; acc[2][3] += a.z*bq.w;
      acc[3][0] += a.w*bq.x; acc[3][1] += a.w*bq.y; acc[3][2] += a.w*bq.z; acc[3][3] += a.w*bq.w;
    }
    __syncthreads();
  }
#pragma unroll
  for (int i = 0; i < 4; ++i) {
    float4 o = {acc[i][0], acc[i][1], acc[i][2], acc[i][3]};
    if (BIAS) {
      float4 bb = *(const float4*)&bias[bn + tn];
      o.x += bb.x; o.y += bb.y; o.z += bb.z; o.w += bb.w;
    }
    if (RELU) {
      o.x = fmaxf(o.x, 0.f); o.y = fmaxf(o.y, 0.f);
      o.z = fmaxf(o.z, 0.f); o.w = fmaxf(o.w, 0.f);
    }
    *(float4*)&C[(size_t)(bm + tm + i) * N + bn + tn] = o;
  }
}

// ---------------- fused relative attention ----------------
// grid (LL/QB, NH, BB), 256 threads.
// logit(q,k) = (q+rr).k  +  (q+rr).pe[k-q+L]  +  d2[n][k-q+L]
// online softmax over k tiles; out = P@V, written [b,q,n,d].
__global__ __launch_bounds__(256) void attn_kernel(
    const float* __restrict__ qv,    // [MM][2*DM] (q cols 0..DM-1, v cols DM..)
    const float* __restrict__ hk,    // [MM][DM] keys = layer input
    const float* __restrict__ rrb,   // [NH][HD] layer slice of r_r_bias
    const float* __restrict__ pe,    // [PEN][HD]
    const int*   __restrict__ mask,  // [BB][LL]
    const float* __restrict__ d2,    // [NH][PEN]
    float* __restrict__ outp)        // [MM][DM]
{
  const int qt = blockIdx.x, n = blockIdx.y, b = blockIdx.z;
  const int q0 = qt * QB;
  const int t  = threadIdx.x;

  __shared__ float qa_s[QB][HD+4];
  __shared__ float ks_s[KB][HD+4];
  __shared__ float vs_s[KB][HD+4];
  __shared__ float pe_s[48][HD+4];
  __shared__ float S_s[QB][KB+4];
  __shared__ float d2_s[48];

  // stage qa = q + rr (once)
#pragma unroll
  for (int i = 0; i < 2; ++i) {
    int g = t + i*256;
    int row = g >> 5, c4 = (g & 31) * 4;
    float4 qr = *(const float4*)&qv[(size_t)(b*LL + q0 + row)*(2*DM) + n*HD + c4];
    float4 rv = *(const float4*)&rrb[n*HD + c4];
    float4 o = {qr.x+rv.x, qr.y+rv.y, qr.z+rv.z, qr.w+rv.w};
    *(float4*)&qa_s[row][c4] = o;
  }

  const int qi = t >> 4;   // 0..15 query row (both phases)
  const int kq = t & 15;   // logit phase: k pair index
  const int dg = t & 15;   // pv phase: d group (8 floats)

  float m_run = -3.0e38f, l_run = 0.f;
  float oa[8] = {0.f,0.f,0.f,0.f,0.f,0.f,0.f,0.f};

  for (int kt = 0; kt < LL/KB; ++kt) {
    const int k0 = kt * KB;
    const int base = k0 - q0 + (LL - QB + 1);   // pe row of j=0 (=497 offset form)
    __syncthreads();   // previous iteration done with ks/vs/pe/S
    // stage K and V tiles
#pragma unroll
    for (int i = 0; i < 4; ++i) {
      int g = t + i*256; int row = g >> 5, c4 = (g & 31) * 4;
      *(float4*)&ks_s[row][c4] =
          *(const float4*)&hk[(size_t)(b*LL + k0 + row)*DM + n*HD + c4];
      *(float4*)&vs_s[row][c4] =
          *(const float4*)&qv[(size_t)(b*LL + k0 + row)*(2*DM) + DM + n*HD + c4];
    }
    // stage pe band (48 rows; row 47 may be clamped, never read)
#pragma unroll
    for (int i = 0; i < 6; ++i) {
      int g = t + i*256; int row = g >> 5, c4 = (g & 31) * 4;
      int pr = base + row; pr = pr > PEN-1 ? PEN-1 : pr;
      *(float4*)&pe_s[row][c4] = *(const float4*)&pe[(size_t)pr*HD + c4];
    }
    if (t < 48) {
      int pr = base + t; pr = pr > PEN-1 ? PEN-1 : pr;
      d2_s[t] = d2[n*PEN + pr];
    }
    __syncthreads();

    // ---- logits: each thread does 2 adjacent k columns for one q row ----
    {
      const int kc0 = kq*2, kc1 = kc0 + 1;
      const int j0 = kc0 - qi + (QB - 1);       // 0..45
      float ak0=0.f, ak1=0.f, ap0=0.f, ap1=0.f;
      const float4* qa4 = (const float4*)qa_s[qi];
      const float4* k04 = (const float4*)ks_s[kc0];
      const float4* k14 = (const float4*)ks_s[kc1];
      const float4* p04 = (const float4*)pe_s[j0];
      const float4* p14 = (const float4*)pe_s[j0+1];
#pragma unroll 8
      for (int d4 = 0; d4 < HD/4; ++d4) {
        float4 a  = qa4[d4];
        float4 kA = k04[d4]; float4 kB = k14[d4];
        float4 pA = p04[d4]; float4 pB = p14[d4];
        ak0 += a.x*kA.x + a.y*kA.y + a.z*kA.z + a.w*kA.w;
        ak1 += a.x*kB.x + a.y*kB.y + a.z*kB.z + a.w*kB.w;
        ap0 += a.x*pA.x + a.y*pA.y + a.z*pA.z + a.w*pA.w;
        ap1 += a.x*pB.x + a.y*pB.y + a.z*pB.z + a.w*pB.w;
      }
      float s0 = ak0 + ap0 + d2_s[j0];
      float s1 = ak1 + ap1 + d2_s[j0+1];
      if (mask[b*LL + k0 + kc0] == 0) s0 = -1e30f;
      if (mask[b*LL + k0 + kc1] == 0) s1 = -1e30f;
      S_s[qi][kc0] = s0; S_s[qi][kc1] = s1;
    }
    __syncthreads();

    // ---- online softmax + P@V (16 threads per q row, 8 dims each) ----
    {
      float mt = -3.0e38f;
#pragma unroll
      for (int kc = 0; kc < KB; ++kc) mt = fmaxf(mt, S_s[qi][kc]);
      float mnew = fmaxf(m_run, mt);
      float sc = __expf(m_run - mnew);
      m_run = mnew;
      l_run *= sc;
#pragma unroll
      for (int j = 0; j < 8; ++j) oa[j] *= sc;
#pragma unroll 4
      for (int kc = 0; kc < KB; ++kc) {
        float p = __expf(S_s[qi][kc] - mnew);
        l_run += p;
        float4 v1 = *(const float4*)&vs_s[kc][dg*8];
        float4 v2 = *(const float4*)&vs_s[kc][dg*8 + 4];
        oa[0] += p*v1.x; oa[1] += p*v1.y; oa[2] += p*v1.z; oa[3] += p*v1.w;
        oa[4] += p*v2.x; oa[5] += p*v2.y; oa[6] += p*v2.z; oa[7] += p*v2.w;
      }
    }
  }
  float inv = 1.0f / l_run;
  float4 w1 = {oa[0]*inv, oa[1]*inv, oa[2]*inv, oa[3]*inv};
  float4 w2 = {oa[4]*inv, oa[5]*inv, oa[6]*inv, oa[7]*inv};
  size_t orow = (size_t)(b*LL + q0 + qi)*DM + n*HD + dg*8;
  *(float4*)&outp[orow]     = w1;
  *(float4*)&outp[orow + 4] = w2;
}

// ---------------- residual add + layernorm (row per block) ----------------
__global__ __launch_bounds__(256) void add_ln_kernel(
    const float* __restrict__ y, const float* __restrict__ res,
    const float* __restrict__ g, const float* __restrict__ bt,
    float* __restrict__ out)
{
  const int r = blockIdx.x, t = threadIdx.x;
  float4 v = *(const float4*)&y[(size_t)r*DM + t*4];
  float4 w = *(const float4*)&res[(size_t)r*DM + t*4];
  float4 s = {v.x+w.x, v.y+w.y, v.z+w.z, v.w+w.w};
  float sum = s.x + s.y + s.z + s.w;
  float ssq = s.x*s.x + s.y*s.y + s.z*s.z + s.w*s.w;
#pragma unroll
  for (int off = 32; off >= 1; off >>= 1) {
    sum += __shfl_down(sum, off);
    ssq += __shfl_down(ssq, off);
  }
  __shared__ float red[8];
  int wid = t >> 6;
  if ((t & 63) == 0) { red[wid] = sum; red[wid+4] = ssq; }
  __syncthreads();
  float totS = red[0] + red[1] + red[2] + red[3];
  float totQ = red[4] + red[5] + red[6] + red[7];
  float mu  = totS * (1.0f/DM);
  float var = totQ * (1.0f/DM) - mu*mu;
  float inv = rsqrtf(var + 1e-5f);
  float4 gg = *(const float4*)&g[t*4];
  float4 bb = *(const float4*)&bt[t*4];
  float4 o;
  o.x = (s.x - mu)*inv*gg.x + bb.x;
  o.y = (s.y - mu)*inv*gg.y + bb.y;
  o.z = (s.z - mu)*inv*gg.z + bb.z;
  o.w = (s.w - mu)*inv*gg.w + bb.w;
  *(float4*)&out[(size_t)r*DM + t*4] = o;
}

extern "C" void kernel_launch(void* const* d_in, const int* in_sizes, int n_in,
                              void* d_out, int out_size, void* d_ws, size_t ws_size,
                              hipStream_t stream) {
  const float* x    = (const float*)d_in[0];
  const int*   mask = (const int*)d_in[1];
  const float* qv_w = (const float*)d_in[2];
  const float* rrb  = (const float*)d_in[3];
  const float* rwb  = (const float*)d_in[4];
  const float* ln1g = (const float*)d_in[5];
  const float* ln1b = (const float*)d_in[6];
  const float* ffnw = (const float*)d_in[7];
  const float* ffnb = (const float*)d_in[8];
  const float* ln2g = (const float*)d_in[9];
  const float* ln2b = (const float*)d_in[10];

  float* h  = (float*)d_out;          // running hidden state [MM][DM]
  float* ws = (float*)d_ws;
  float* pe  = ws;                               // 131072
  float* d2  = pe + (size_t)PEN*HD;              // 8192
  float* qv  = d2 + (size_t)NH*PEN;              // 8388608
  float* tmp = qv + (size_t)MM*2*DM;             // 4194304
  // requires ws_size >= 50,888,704 bytes

  hipMemcpyAsync(h, x, (size_t)MM*DM*sizeof(float), hipMemcpyDeviceToDevice, stream);
  pe_kernel<<<(PEN*HD)/256, 256, 0, stream>>>(pe);

  for (int l = 0; l < NL; ++l) {
    const float* rr_l = rrb + (size_t)l*NH*HD;
    const float* rw_l = rwb + (size_t)l*NH*HD;
    d2_kernel<<<(NH*PEN)/256, 256, 0, stream>>>(rr_l, rw_l, pe, d2);
    // qv = h @ qv_w[l]^T   [4096 x 2048]
    gemm_nt<false,false><<<dim3((2*DM)/64, MM/64), 256, 0, stream>>>(
        h, qv_w + (size_t)l*2*DM*DM, nullptr, qv, MM, 2*DM, DM);
    // fused relative attention -> tmp (layout b,q,n,d)
    attn_kernel<<<dim3(LL/QB, NH, BB), 256, 0, stream>>>(
        qv, h, rr_l, pe, mask, d2, tmp);
    // h = LN1(tmp + h)
    add_ln_kernel<<<MM, 256, 0, stream>>>(tmp, h, ln1g + (size_t)l*DM, ln1b + (size_t)l*DM, h);
    // tmp = relu(h @ ffn_w[l]^T + ffn_b[l])
    gemm_nt<true,true><<<dim3(DM/64, MM/64), 256, 0, stream>>>(
        h, ffnw + (size_t)l*DM*DM, ffnb + (size_t)l*DM, tmp, MM, DM, DM);
    // h = LN2(tmp + h)
    add_ln_kernel<<<MM, 256, 0, stream>>>(tmp, h, ln2g + (size_t)l*DM, ln2b + (size_t)l*DM, h);
  }
  (void)in_sizes; (void)n_in; (void)out_size; (void)ws_size;
}

// Round 3
// 2168.619 us; speedup vs baseline: 1.6808x; 1.6808x over previous
//
#include <hip/hip_runtime.h>
#include <math.h>

#define NL 4
#define DM 1024
#define NH 8
#define HD 128
#define BB 8
#define LL 512
#define MM (BB*LL)      // 4096 rows
#define PEN (2*LL)      // 1024 pe rows
#define QB 16           // query tile
#define KB 32           // key tile

typedef __attribute__((ext_vector_type(8))) __bf16 bf16x8;
typedef __attribute__((ext_vector_type(4))) float f32x4;

// ---------------- helpers ----------------
__device__ __forceinline__ unsigned short f2b(float f) {   // RNE f32->bf16
  unsigned int u = __float_as_uint(f);
  u = (u + 0x7FFFu + ((u >> 16) & 1u)) >> 16;
  return (unsigned short)u;
}
__device__ __forceinline__ float b2f(unsigned short s) {
  return __uint_as_float(((unsigned int)s) << 16);
}
__device__ __forceinline__ void glds16(const void* g, void* l) {
  __builtin_amdgcn_global_load_lds(
      (const __attribute__((address_space(1))) unsigned int*)g,
      (__attribute__((address_space(3))) unsigned int*)l, 16, 0, 0);
}

// ---------------- relative position embedding ----------------
__global__ __launch_bounds__(256) void pe_kernel(float* __restrict__ pe) {
  int idx = blockIdx.x * 256 + threadIdx.x;
  if (idx >= PEN * HD) return;
  int p = idx / HD, j = idx % HD;
  int tt = (j < 64) ? j : (j - 64);
  float invf = expf((float)tt * (-9.210340371976184f / 63.0f));
  float ang = (float)(p - LL) * invf;
  pe[idx] = (j < 64) ? sinf(ang) : cosf(ang);
}

// ---------------- d2[n][p] = (rw[n]-rr[n]) . pe[p] ----------------
__global__ __launch_bounds__(256) void d2_kernel(const float* __restrict__ rrb,
                                                 const float* __restrict__ rwb,
                                                 const float* __restrict__ pe,
                                                 float* __restrict__ d2) {
  int idx = blockIdx.x * 256 + threadIdx.x;
  if (idx >= NH * PEN) return;
  int n = idx / PEN, p = idx % PEN;
  float s = 0.f;
  for (int d = 0; d < HD; ++d)
    s += (rwb[n*HD + d] - rrb[n*HD + d]) * pe[p*HD + d];
  d2[idx] = s;
}

// ---------------- split f32 -> (hi,lo) bf16 pair, RNE ----------------
__global__ __launch_bounds__(256) void split_kernel(const float* __restrict__ in,
                                                    unsigned short* __restrict__ hi,
                                                    unsigned short* __restrict__ lo,
                                                    int n) {
  int i = (blockIdx.x * 256 + threadIdx.x) * 4;
  if (i >= n) return;
  float4 v = *(const float4*)&in[i];
  float x[4] = {v.x, v.y, v.z, v.w};
  ushort4 h4, l4;
  unsigned short* hp = (unsigned short*)&h4;
  unsigned short* lp = (unsigned short*)&l4;
#pragma unroll
  for (int e = 0; e < 4; ++e) {
    unsigned short h = f2b(x[e]);
    hp[e] = h;
    lp[e] = f2b(x[e] - b2f(h));
  }
  *(ushort4*)&hi[i] = h4;
  *(ushort4*)&lo[i] = l4;
}

// ---------------- split-bf16 MFMA GEMM: C = A[M][K] @ Bw[N][K]^T -----------
// A pre-split (hi/lo bf16); B f32 global, split in-register during staging.
// acc += Ah*Bh + Ah*Bl + Al*Bh  (error ~2^-16, f32-class for this problem).
// 128x128 tile, BK=32, 256 threads (4 waves), wave = 64x64 out (4x4 frags).
// Output f32 with row stride ldc; FFN adds bias+relu.
template<bool FFN>
__global__ __launch_bounds__(256) void gemm_mfma(
    const unsigned short* __restrict__ Ah, const unsigned short* __restrict__ Al,
    const float* __restrict__ Bw, const float* __restrict__ bias,
    float* __restrict__ C, int N, int K, int ldc) {
  __shared__ __align__(16) unsigned short AsH[128*32];
  __shared__ __align__(16) unsigned short AsL[128*32];
  __shared__ __align__(16) unsigned short BsH[128*40];  // pad 32->40: 16B-aligned rows
  __shared__ __align__(16) unsigned short BsL[128*40];
  const int t = threadIdx.x;
  const int w = t >> 6, l = t & 63;
  const int bm = blockIdx.y * 128, bn = blockIdx.x * 128;
  const int wr = (w >> 1) * 64, wc = (w & 1) * 64;

  // A async staging: thread t covers row t>>2 (+64), k-chunk (t&3)*8
  const unsigned short* Ahb = Ah + (size_t)(bm + (t >> 2)) * K + (t & 3) * 8;
  const unsigned short* Alb = Al + (size_t)(bm + (t >> 2)) * K + (t & 3) * 8;
  unsigned short* AsHw0 = &AsH[w * 512];
  unsigned short* AsHw1 = &AsH[2048 + w * 512];
  unsigned short* AsLw0 = &AsL[w * 512];
  unsigned short* AsLw1 = &AsL[2048 + w * 512];

  // B reg staging: thread t covers row t>>1, half (t&1)*16 (16 f32)
  const int brow = t >> 1, bhalf = (t & 1) * 16;
  const float* Bb = Bw + (size_t)(bn + brow) * K + bhalf;

  f32x4 acc[4][4] = {};
  const int lm = l & 15;
  const int lk = (l >> 4) * 8;

  for (int k0 = 0; k0 < K; k0 += 32) {
    // B tile global->reg (issues early, hides latency under prior barrier)
    float4 bv[4];
#pragma unroll
    for (int c = 0; c < 4; ++c)
      bv[c] = *(const float4*)(Bb + k0 + c*4);
    // A async global->LDS
    glds16(Ahb + k0,                 AsHw0);
    glds16(Ahb + (size_t)64*K + k0,  AsHw1);
    glds16(Alb + k0,                 AsLw0);
    glds16(Alb + (size_t)64*K + k0,  AsLw1);
    // B split (trunc hi / trunc lo; combined error <= 2^-16) & LDS write
#pragma unroll
    for (int c = 0; c < 4; ++c) {
      float xs[4] = {bv[c].x, bv[c].y, bv[c].z, bv[c].w};
      ushort4 h4, l4;
      unsigned short* hp = (unsigned short*)&h4;
      unsigned short* lp = (unsigned short*)&l4;
#pragma unroll
      for (int e = 0; e < 4; ++e) {
        unsigned u = __float_as_uint(xs[e]);
        hp[e] = (unsigned short)(u >> 16);
        float r = xs[e] - __uint_as_float(u & 0xffff0000u);
        lp[e] = (unsigned short)(__float_as_uint(r) >> 16);
      }
      *(ushort4*)&BsH[brow*40 + bhalf + c*4] = h4;
      *(ushort4*)&BsL[brow*40 + bhalf + c*4] = l4;
    }
    __syncthreads();

    bf16x8 afh[4], afl[4], bfh[4], bfl[4];
#pragma unroll
    for (int i = 0; i < 4; ++i) {
      afh[i] = *(const bf16x8*)&AsH[(wr + i*16 + lm) * 32 + lk];
      afl[i] = *(const bf16x8*)&AsL[(wr + i*16 + lm) * 32 + lk];
    }
#pragma unroll
    for (int j = 0; j < 4; ++j) {
      bfh[j] = *(const bf16x8*)&BsH[(wc + j*16 + lm) * 40 + lk];
      bfl[j] = *(const bf16x8*)&BsL[(wc + j*16 + lm) * 40 + lk];
    }
#pragma unroll
    for (int i = 0; i < 4; ++i)
#pragma unroll
      for (int j = 0; j < 4; ++j) {
        acc[i][j] = __builtin_amdgcn_mfma_f32_16x16x32_bf16(afh[i], bfh[j], acc[i][j], 0, 0, 0);
        acc[i][j] = __builtin_amdgcn_mfma_f32_16x16x32_bf16(afh[i], bfl[j], acc[i][j], 0, 0, 0);
        acc[i][j] = __builtin_amdgcn_mfma_f32_16x16x32_bf16(afl[i], bfh[j], acc[i][j], 0, 0, 0);
      }
    __syncthreads();
  }

  // C/D layout: col = lane&15, row = (lane>>4)*4 + reg
  const int cr = (l >> 4) * 4;
#pragma unroll
  for (int i = 0; i < 4; ++i) {
#pragma unroll
    for (int j = 0; j < 4; ++j) {
      int row = bm + wr + i*16 + cr;
      int col = bn + wc + j*16 + lm;
      float bvl = FFN ? bias[col] : 0.f;
      f32x4 a = acc[i][j];
#pragma unroll
      for (int r4 = 0; r4 < 4; ++r4) {
        float v = a[r4];
        if (FFN) v = fmaxf(v + bvl, 0.f);
        C[(size_t)(row + r4) * ldc + col] = v;
      }
    }
  }
}

// ---------------- fused relative attention (all f32 math) ----------------
// grid (LL/QB, NH, BB), 256 threads.
// logit(q,k) = (q+rr).k + (q+rr).pe[k-q+L] + d2[n][k-q+L]
// Output written into the q-half of qv (block-exclusive rows/cols; q is
// staged to LDS before any write, v-half untouched).
__global__ __launch_bounds__(256) void attn_kernel(
    const float* __restrict__ qv,    // [MM][2*DM] f32 (q | v)
    const float* __restrict__ hk,    // [MM][DM] keys = layer input (f32)
    const float* __restrict__ rrb,   // [NH][HD]
    const float* __restrict__ pe,    // [PEN][HD]
    const int*   __restrict__ mask,  // [BB][LL]
    const float* __restrict__ d2,    // [NH][PEN]
    float* __restrict__ outp)        // = qv (writes q-half, stride 2*DM)
{
  const int qt = blockIdx.x, n = blockIdx.y, b = blockIdx.z;
  const int q0 = qt * QB;
  const int t  = threadIdx.x;

  __shared__ __align__(16) float qa_s[QB][HD+4];
  __shared__ __align__(16) float ks_s[KB][HD+4];
  __shared__ __align__(16) float vs_s[KB][HD+4];
  __shared__ __align__(16) float pe_s[48][HD+4];
  __shared__ float S_s[QB][KB+4];
  __shared__ float d2_s[48];

  // stage qa = q + rr : 16 x 128 f32
#pragma unroll
  for (int i = 0; i < 2; ++i) {
    int g = t + i*256;
    int row = g >> 5, c4 = (g & 31) * 4;
    float4 qr = *(const float4*)&qv[(size_t)(b*LL + q0 + row)*(2*DM) + n*HD + c4];
    float4 rv = *(const float4*)&rrb[n*HD + c4];
    float4 o = {qr.x+rv.x, qr.y+rv.y, qr.z+rv.z, qr.w+rv.w};
    *(float4*)&qa_s[row][c4] = o;
  }

  const int qi = t >> 4;   // 0..15 query row
  const int kq = t & 15;   // logit: cols (kq, kq+16); pv: d group
  const int dg = t & 15;

  float m_run = -3.0e38f, l_run = 0.f;
  float oa[8] = {0.f,0.f,0.f,0.f,0.f,0.f,0.f,0.f};

  for (int kt = 0; kt < LL/KB; ++kt) {
    const int k0 = kt * KB;
    const int base = k0 - q0 + (LL - QB + 1);
    __syncthreads();   // previous iteration done with ks/vs/S
    // stage K (f32) : 32x128
#pragma unroll
    for (int i = 0; i < 4; ++i) {
      int g = t + i*256; int row = g >> 5, c4 = (g & 31) * 4;
      *(float4*)&ks_s[row][c4] =
          *(const float4*)&hk[(size_t)(b*LL + k0 + row)*DM + n*HD + c4];
    }
    // stage V (f32) : 32x128
#pragma unroll
    for (int i = 0; i < 4; ++i) {
      int g = t + i*256; int row = g >> 5, c4 = (g & 31) * 4;
      *(float4*)&vs_s[row][c4] =
          *(const float4*)&qv[(size_t)(b*LL + k0 + row)*(2*DM) + DM + n*HD + c4];
    }
    // stage pe band (48 rows; clamped rows never read)
#pragma unroll
    for (int i = 0; i < 6; ++i) {
      int g = t + i*256; int row = g >> 5, c4 = (g & 31) * 4;
      int pr = base + row; pr = pr > PEN-1 ? PEN-1 : pr;
      *(float4*)&pe_s[row][c4] = *(const float4*)&pe[(size_t)pr*HD + c4];
    }
    if (t < 48) {
      int pr = base + t; pr = pr > PEN-1 ? PEN-1 : pr;
      d2_s[t] = d2[n*PEN + pr];
    }
    __syncthreads();

    // ---- logits: thread (qi,kq) computes cols kq and kq+16 ----
    float s0, s1;
    {
      const int j0 = kq - qi + (QB - 1);        // 0..30, j1 = j0+16 <= 46
      float ak0=0.f, ak1=0.f, ap0=0.f, ap1=0.f;
      const float4* qa4 = (const float4*)qa_s[qi];
      const float4* k04 = (const float4*)ks_s[kq];
      const float4* k14 = (const float4*)ks_s[kq+16];
      const float4* p04 = (const float4*)pe_s[j0];
      const float4* p14 = (const float4*)pe_s[j0+16];
#pragma unroll 8
      for (int d4 = 0; d4 < HD/4; ++d4) {
        float4 a  = qa4[d4];
        float4 kA = k04[d4]; float4 kB = k14[d4];
        float4 pA = p04[d4]; float4 pB = p14[d4];
        ak0 += a.x*kA.x + a.y*kA.y + a.z*kA.z + a.w*kA.w;
        ak1 += a.x*kB.x + a.y*kB.y + a.z*kB.z + a.w*kB.w;
        ap0 += a.x*pA.x + a.y*pA.y + a.z*pA.z + a.w*pA.w;
        ap1 += a.x*pB.x + a.y*pB.y + a.z*pB.z + a.w*pB.w;
      }
      s0 = ak0 + ap0 + d2_s[j0];
      s1 = ak1 + ap1 + d2_s[j0+16];
      if (mask[b*LL + k0 + kq]      == 0) s0 = -1e30f;
      if (mask[b*LL + k0 + kq + 16] == 0) s1 = -1e30f;
    }

    // ---- softmax update: shfl-reduce over the 16 lanes of this q-row ----
    {
      float mt = fmaxf(s0, s1);
      mt = fmaxf(mt, __shfl_xor(mt, 1));
      mt = fmaxf(mt, __shfl_xor(mt, 2));
      mt = fmaxf(mt, __shfl_xor(mt, 4));
      mt = fmaxf(mt, __shfl_xor(mt, 8));
      float mnew = fmaxf(m_run, mt);
      float sc = __expf(m_run - mnew);
      float p0 = __expf(s0 - mnew);
      float p1 = __expf(s1 - mnew);
      float la = p0 + p1;
      la += __shfl_xor(la, 1);
      la += __shfl_xor(la, 2);
      la += __shfl_xor(la, 4);
      la += __shfl_xor(la, 8);
      m_run = mnew;
      l_run = l_run * sc + la;
#pragma unroll
      for (int j = 0; j < 8; ++j) oa[j] *= sc;
      S_s[qi][kq]      = p0;   // same-wave write->read, LDS ops in-order
      S_s[qi][kq + 16] = p1;
    }

    // ---- P@V : thread (qi,dg) accumulates cols dg*4 and 64+dg*4 ----
#pragma unroll 4
    for (int kc = 0; kc < KB; ++kc) {
      float p = S_s[qi][kc];
      float4 v1 = *(const float4*)&vs_s[kc][dg*4];
      float4 v2 = *(const float4*)&vs_s[kc][64 + dg*4];
      oa[0] += p*v1.x; oa[1] += p*v1.y; oa[2] += p*v1.z; oa[3] += p*v1.w;
      oa[4] += p*v2.x; oa[5] += p*v2.y; oa[6] += p*v2.z; oa[7] += p*v2.w;
    }
  }
  float inv = 1.0f / l_run;
  float4 w1 = {oa[0]*inv, oa[1]*inv, oa[2]*inv, oa[3]*inv};
  float4 w2 = {oa[4]*inv, oa[5]*inv, oa[6]*inv, oa[7]*inv};
  size_t orow = (size_t)(b*LL + q0 + qi)*(2*DM) + n*HD;   // q-half slot
  *(float4*)&outp[orow + dg*4]      = w1;
  *(float4*)&outp[orow + 64 + dg*4] = w2;
}

// ------- residual add + layernorm (+ split hi/lo bf16 for next GEMM) -------
__global__ __launch_bounds__(256) void add_ln_kernel(
    const float* __restrict__ y, int ys,
    const float* __restrict__ res,
    const float* __restrict__ g, const float* __restrict__ bt,
    float* __restrict__ out,
    unsigned short* __restrict__ ohi, unsigned short* __restrict__ olo)
{
  const int r = blockIdx.x, t = threadIdx.x;
  float4 v = *(const float4*)&y[(size_t)r*ys + t*4];
  float4 w = *(const float4*)&res[(size_t)r*DM + t*4];
  float4 s = {v.x+w.x, v.y+w.y, v.z+w.z, v.w+w.w};
  float sum = s.x + s.y + s.z + s.w;
  float ssq = s.x*s.x + s.y*s.y + s.z*s.z + s.w*s.w;
#pragma unroll
  for (int off = 32; off >= 1; off >>= 1) {
    sum += __shfl_down(sum, off);
    ssq += __shfl_down(ssq, off);
  }
  __shared__ float red[8];
  int wid = t >> 6;
  if ((t & 63) == 0) { red[wid] = sum; red[wid+4] = ssq; }
  __syncthreads();
  float totS = red[0] + red[1] + red[2] + red[3];
  float totQ = red[4] + red[5] + red[6] + red[7];
  float mu  = totS * (1.0f/DM);
  float var = totQ * (1.0f/DM) - mu*mu;
  float inv = rsqrtf(var + 1e-5f);
  float4 gg = *(const float4*)&g[t*4];
  float4 bb = *(const float4*)&bt[t*4];
  float4 o;
  o.x = (s.x - mu)*inv*gg.x + bb.x;
  o.y = (s.y - mu)*inv*gg.y + bb.y;
  o.z = (s.z - mu)*inv*gg.z + bb.z;
  o.w = (s.w - mu)*inv*gg.w + bb.w;
  *(float4*)&out[(size_t)r*DM + t*4] = o;
  float xs[4] = {o.x, o.y, o.z, o.w};
  ushort4 h4, l4;
  unsigned short* hp = (unsigned short*)&h4;
  unsigned short* lp = (unsigned short*)&l4;
#pragma unroll
  for (int e = 0; e < 4; ++e) {
    unsigned short h = f2b(xs[e]);
    hp[e] = h;
    lp[e] = f2b(xs[e] - b2f(h));
  }
  *(ushort4*)&ohi[(size_t)r*DM + t*4] = h4;
  *(ushort4*)&olo[(size_t)r*DM + t*4] = l4;
}

extern "C" void kernel_launch(void* const* d_in, const int* in_sizes, int n_in,
                              void* d_out, int out_size, void* d_ws, size_t ws_size,
                              hipStream_t stream) {
  const float* x    = (const float*)d_in[0];
  const int*   mask = (const int*)d_in[1];
  const float* qv_w = (const float*)d_in[2];
  const float* rrb  = (const float*)d_in[3];
  const float* rwb  = (const float*)d_in[4];
  const float* ln1g = (const float*)d_in[5];
  const float* ln1b = (const float*)d_in[6];
  const float* ffnw = (const float*)d_in[7];
  const float* ffnb = (const float*)d_in[8];
  const float* ln2g = (const float*)d_in[9];
  const float* ln2b = (const float*)d_in[10];

  float* h  = (float*)d_out;                     // [MM][DM] hidden (f32)
  float* ws = (float*)d_ws;
  float* pe  = ws;                               // 131072 f32
  float* d2  = pe + (size_t)PEN*HD;              // 8192 f32
  float* qv  = d2 + (size_t)NH*PEN;              // MM*2DM f32 (32 MB)
  unsigned short* hhi = (unsigned short*)(qv + (size_t)MM*2*DM);  // MM*DM bf16
  unsigned short* hlo = hhi + (size_t)MM*DM;                      // MM*DM bf16
  // total = 50,888,704 bytes (same as the round-1 layout that passed)

  hipMemcpyAsync(h, x, (size_t)MM*DM*sizeof(float), hipMemcpyDeviceToDevice, stream);
  split_kernel<<<(MM*DM)/1024, 256, 0, stream>>>(x, hhi, hlo, MM*DM);
  pe_kernel<<<(PEN*HD)/256, 256, 0, stream>>>(pe);

  for (int l = 0; l < NL; ++l) {
    const float* rr_l = rrb + (size_t)l*NH*HD;
    const float* rw_l = rwb + (size_t)l*NH*HD;
    d2_kernel<<<(NH*PEN)/256, 256, 0, stream>>>(rr_l, rw_l, pe, d2);
    // qv (f32) = h @ qv_w^T   [4096 x 2048]
    gemm_mfma<false><<<dim3((2*DM)/128, MM/128), 256, 0, stream>>>(
        hhi, hlo, qv_w + (size_t)l*2*DM*DM, nullptr, qv, 2*DM, DM, 2*DM);
    // fused relative attention -> q-half of qv
    attn_kernel<<<dim3(LL/QB, NH, BB), 256, 0, stream>>>(
        qv, h, rr_l, pe, mask, d2, qv);
    // h = LN1(attn + h), + split
    add_ln_kernel<<<MM, 256, 0, stream>>>(qv, 2*DM, h,
        ln1g + (size_t)l*DM, ln1b + (size_t)l*DM, h, hhi, hlo);
    // ffn out (f32) = relu(h @ ffn_w^T + b) -> v-half of qv
    gemm_mfma<true><<<dim3(DM/128, MM/128), 256, 0, stream>>>(
        hhi, hlo, ffnw + (size_t)l*DM*DM, ffnb + (size_t)l*DM, qv + DM, DM, DM, 2*DM);
    // h = LN2(ffn + h), + split
    add_ln_kernel<<<MM, 256, 0, stream>>>(qv + DM, 2*DM, h,
        ln2g + (size_t)l*DM, ln2b + (size_t)l*DM, h, hhi, hlo);
  }
  (void)in_sizes; (void)n_in; (void)out_size; (void)ws_size;
}

// Round 4
// 1248.368 us; speedup vs baseline: 2.9199x; 1.7372x over previous
//
#include <hip/hip_runtime.h>
#include <math.h>

#define NL 4
#define DM 1024
#define NH 8
#define HD 128
#define BB 8
#define LL 512
#define MM (BB*LL)      // 4096 rows
#define PEN (2*LL)      // 1024 pe rows
#define QT 64           // q rows per attn block
#define KT 32           // k tile
#define NKT (LL/KT)     // 16

typedef __attribute__((ext_vector_type(8))) __bf16 bf16x8;
typedef __attribute__((ext_vector_type(4))) float f32x4;

// ---------------- helpers ----------------
__device__ __forceinline__ unsigned short f2b(float f) {   // RNE f32->bf16
  unsigned int u = __float_as_uint(f);
  u = (u + 0x7FFFu + ((u >> 16) & 1u)) >> 16;
  return (unsigned short)u;
}
__device__ __forceinline__ float b2f(unsigned short s) {
  return __uint_as_float(((unsigned int)s) << 16);
}
__device__ __forceinline__ void glds16(const void* g, void* l) {
  __builtin_amdgcn_global_load_lds(
      (const __attribute__((address_space(1))) unsigned int*)g,
      (__attribute__((address_space(3))) unsigned int*)l, 16, 0, 0);
}
union U8 { unsigned short s[8]; bf16x8 v; };
// trunc-hi / RNE-lo split of 8 floats
__device__ __forceinline__ void split8(const float4& a, const float4& b,
                                       bf16x8& h, bf16x8& l) {
  float x[8] = {a.x,a.y,a.z,a.w,b.x,b.y,b.z,b.w};
  U8 uh, ul;
#pragma unroll
  for (int e = 0; e < 8; ++e) {
    unsigned u = __float_as_uint(x[e]);
    uh.s[e] = (unsigned short)(u >> 16);
    ul.s[e] = f2b(x[e] - __uint_as_float(u & 0xffff0000u));
  }
  h = uh.v; l = ul.v;
}

// ---------------- relative position embedding (split bf16 hi/lo) ----------
__global__ __launch_bounds__(256) void pe_kernel(unsigned short* __restrict__ peh,
                                                 unsigned short* __restrict__ pel) {
  int idx = blockIdx.x * 256 + threadIdx.x;
  if (idx >= PEN * HD) return;
  int p = idx / HD, j = idx % HD;
  int tt = (j < 64) ? j : (j - 64);
  float invf = expf((float)tt * (-9.210340371976184f / 63.0f));
  float ang = (float)(p - LL) * invf;
  float v = (j < 64) ? sinf(ang) : cosf(ang);
  unsigned u = __float_as_uint(v);
  unsigned short h = (unsigned short)(u >> 16);
  peh[idx] = h;
  pel[idx] = f2b(v - b2f(h));
}

// ---------------- d2[n][p] = (rw[n]-rr[n]) . pe[p] ----------------
__global__ __launch_bounds__(256) void d2_kernel(const float* __restrict__ rrb,
                                                 const float* __restrict__ rwb,
                                                 const unsigned short* __restrict__ peh,
                                                 const unsigned short* __restrict__ pel,
                                                 float* __restrict__ d2) {
  int idx = blockIdx.x * 256 + threadIdx.x;
  if (idx >= NH * PEN) return;
  int n = idx / PEN, p = idx % PEN;
  float s = 0.f;
  for (int d = 0; d < HD; ++d) {
    float pv = b2f(peh[p*HD + d]) + b2f(pel[p*HD + d]);
    s += (rwb[n*HD + d] - rrb[n*HD + d]) * pv;
  }
  d2[idx] = s;
}

// ---------------- split f32 -> (hi,lo) bf16 pair, RNE ----------------
__global__ __launch_bounds__(256) void split_kernel(const float* __restrict__ in,
                                                    unsigned short* __restrict__ hi,
                                                    unsigned short* __restrict__ lo,
                                                    int n) {
  int i = (blockIdx.x * 256 + threadIdx.x) * 4;
  if (i >= n) return;
  float4 v = *(const float4*)&in[i];
  float x[4] = {v.x, v.y, v.z, v.w};
  ushort4 h4, l4;
  unsigned short* hp = (unsigned short*)&h4;
  unsigned short* lp = (unsigned short*)&l4;
#pragma unroll
  for (int e = 0; e < 4; ++e) {
    unsigned short h = f2b(x[e]);
    hp[e] = h;
    lp[e] = f2b(x[e] - b2f(h));
  }
  *(ushort4*)&hi[i] = h4;
  *(ushort4*)&lo[i] = l4;
}

// ---------------- split-bf16 MFMA GEMM: C = A[M][K] @ Bw[N][K]^T -----------
template<bool FFN>
__global__ __launch_bounds__(256) void gemm_mfma(
    const unsigned short* __restrict__ Ah, const unsigned short* __restrict__ Al,
    const float* __restrict__ Bw, const float* __restrict__ bias,
    float* __restrict__ C, int N, int K, int ldc) {
  __shared__ __align__(16) unsigned short AsH[128*32];
  __shared__ __align__(16) unsigned short AsL[128*32];
  __shared__ __align__(16) unsigned short BsH[128*40];
  __shared__ __align__(16) unsigned short BsL[128*40];
  const int t = threadIdx.x;
  const int w = t >> 6, l = t & 63;
  const int bm = blockIdx.y * 128, bn = blockIdx.x * 128;
  const int wr = (w >> 1) * 64, wc = (w & 1) * 64;

  const unsigned short* Ahb = Ah + (size_t)(bm + (t >> 2)) * K + (t & 3) * 8;
  const unsigned short* Alb = Al + (size_t)(bm + (t >> 2)) * K + (t & 3) * 8;
  unsigned short* AsHw0 = &AsH[w * 512];
  unsigned short* AsHw1 = &AsH[2048 + w * 512];
  unsigned short* AsLw0 = &AsL[w * 512];
  unsigned short* AsLw1 = &AsL[2048 + w * 512];

  const int brow = t >> 1, bhalf = (t & 1) * 16;
  const float* Bb = Bw + (size_t)(bn + brow) * K + bhalf;

  f32x4 acc[4][4] = {};
  const int lm = l & 15;
  const int lk = (l >> 4) * 8;

  for (int k0 = 0; k0 < K; k0 += 32) {
    float4 bv[4];
#pragma unroll
    for (int c = 0; c < 4; ++c)
      bv[c] = *(const float4*)(Bb + k0 + c*4);
    glds16(Ahb + k0,                 AsHw0);
    glds16(Ahb + (size_t)64*K + k0,  AsHw1);
    glds16(Alb + k0,                 AsLw0);
    glds16(Alb + (size_t)64*K + k0,  AsLw1);
#pragma unroll
    for (int c = 0; c < 4; ++c) {
      float xs[4] = {bv[c].x, bv[c].y, bv[c].z, bv[c].w};
      ushort4 h4, l4;
      unsigned short* hp = (unsigned short*)&h4;
      unsigned short* lp = (unsigned short*)&l4;
#pragma unroll
      for (int e = 0; e < 4; ++e) {
        unsigned u = __float_as_uint(xs[e]);
        hp[e] = (unsigned short)(u >> 16);
        float r = xs[e] - __uint_as_float(u & 0xffff0000u);
        lp[e] = (unsigned short)(__float_as_uint(r) >> 16);
      }
      *(ushort4*)&BsH[brow*40 + bhalf + c*4] = h4;
      *(ushort4*)&BsL[brow*40 + bhalf + c*4] = l4;
    }
    __syncthreads();

    bf16x8 afh[4], afl[4], bfh[4], bfl[4];
#pragma unroll
    for (int i = 0; i < 4; ++i) {
      afh[i] = *(const bf16x8*)&AsH[(wr + i*16 + lm) * 32 + lk];
      afl[i] = *(const bf16x8*)&AsL[(wr + i*16 + lm) * 32 + lk];
    }
#pragma unroll
    for (int j = 0; j < 4; ++j) {
      bfh[j] = *(const bf16x8*)&BsH[(wc + j*16 + lm) * 40 + lk];
      bfl[j] = *(const bf16x8*)&BsL[(wc + j*16 + lm) * 40 + lk];
    }
#pragma unroll
    for (int i = 0; i < 4; ++i)
#pragma unroll
      for (int j = 0; j < 4; ++j) {
        acc[i][j] = __builtin_amdgcn_mfma_f32_16x16x32_bf16(afh[i], bfh[j], acc[i][j], 0, 0, 0);
        acc[i][j] = __builtin_amdgcn_mfma_f32_16x16x32_bf16(afh[i], bfl[j], acc[i][j], 0, 0, 0);
        acc[i][j] = __builtin_amdgcn_mfma_f32_16x16x32_bf16(afl[i], bfh[j], acc[i][j], 0, 0, 0);
      }
    __syncthreads();
  }

  const int cr = (l >> 4) * 4;
#pragma unroll
  for (int i = 0; i < 4; ++i) {
#pragma unroll
    for (int j = 0; j < 4; ++j) {
      int row = bm + wr + i*16 + cr;
      int col = bn + wc + j*16 + lm;
      float bvl = FFN ? bias[col] : 0.f;
      f32x4 a = acc[i][j];
#pragma unroll
      for (int r4 = 0; r4 < 4; ++r4) {
        float v = a[r4];
        if (FFN) v = fmaxf(v + bvl, 0.f);
        C[(size_t)(row + r4) * ldc + col] = v;
      }
    }
  }
}

// ================= MFMA fused relative attention =================
// grid (LL/QT=8, NH, BB), 256 threads = 4 waves; wave w owns q-rows
// [q0+16w, q0+16w+16). logit = qa.k + qa.pe[k-q+512] + d2[n][k-q+512],
// qa = q + rr. AC & pe-term & PV all 3-pass split-bf16 MFMA (f32-class).
__global__ __launch_bounds__(256) void attn_mfma(
    const float* __restrict__ qv,           // [MM][2048] f32 (q | v)
    const unsigned short* __restrict__ khp, // keys hi  [MM][1024]
    const unsigned short* __restrict__ klp, // keys lo
    const unsigned short* __restrict__ pehp,// [1024][128]
    const unsigned short* __restrict__ pelp,
    const float* __restrict__ rrb,          // [NH][128] layer slice
    const int*   __restrict__ mask,         // [BB][LL]
    const float* __restrict__ d2p,          // [NH][1024]
    float* __restrict__ outp)               // = qv (q-half, stride 2048)
{
  __shared__ __align__(16) unsigned short KsH[KT*136];
  __shared__ __align__(16) unsigned short KsL[KT*136];
  __shared__ __align__(16) unsigned short VtH[HD*40];
  __shared__ __align__(16) unsigned short VtL[HD*40];
  __shared__ __align__(16) unsigned short PeH[128*136];
  __shared__ __align__(16) unsigned short PeL[128*136];
  __shared__ float Bsc[4][16*48];
  __shared__ __align__(16) unsigned short PsH[4][16*40];
  __shared__ __align__(16) unsigned short PsL[4][16*40];
  __shared__ int mask_s[LL];

  const int q0 = blockIdx.x * QT;
  const int n  = blockIdx.y, b = blockIdx.z;
  const int t  = threadIdx.x;
  const int w  = t >> 6, l = t & 63;
  const int lm = l & 15, lg = l >> 4;
  const int q0w = q0 + w*16;
  const int r8 = t >> 3, s8 = t & 7;        // staging row / 16-short seg
  const int vr0 = t >> 5, vd4 = (t & 31)*4; // V staging

  if (t < 128) *(int4*)&mask_s[t*4] = *(const int4*)&mask[b*LL + t*4];

  // ---- qa A-frags in registers (split hi/lo) ----
  bf16x8 qah[4], qal[4];
  {
    size_t qrow = (size_t)(b*LL + q0w + lm) * (2*DM) + (size_t)n*HD;
#pragma unroll
    for (int c = 0; c < 4; ++c) {
      int d0 = c*32 + lg*8;
      float4 x1 = *(const float4*)&qv[qrow + d0];
      float4 x2 = *(const float4*)&qv[qrow + d0 + 4];
      float4 r1 = *(const float4*)&rrb[n*HD + d0];
      float4 r2 = *(const float4*)&rrb[n*HD + d0 + 4];
      float4 a = {x1.x+r1.x, x1.y+r1.y, x1.z+r1.z, x1.w+r1.w};
      float4 bq = {x2.x+r2.x, x2.y+r2.y, x2.z+r2.z, x2.w+r2.w};
      split8(a, bq, qah[c], qal[c]);
    }
  }

  // ---- prologue staging: pe window [U0, U0+96), K/V tile 0 ----
  const int U0 = 449 - q0;
#pragma unroll
  for (int i = 0; i < 3; ++i) {
    int prow = U0 + 32*i + r8;
    int prc = prow < 0 ? 0 : (prow > PEN-1 ? PEN-1 : prow);
    uint4 a0 = *(const uint4*)&pehp[(size_t)prc*HD + s8*16];
    uint4 a1 = *(const uint4*)&pehp[(size_t)prc*HD + s8*16 + 8];
    uint4 c0 = *(const uint4*)&pelp[(size_t)prc*HD + s8*16];
    uint4 c1 = *(const uint4*)&pelp[(size_t)prc*HD + s8*16 + 8];
    int slot = prow & 127;
    *(uint4*)&PeH[slot*136 + s8*16]     = a0;
    *(uint4*)&PeH[slot*136 + s8*16 + 8] = a1;
    *(uint4*)&PeL[slot*136 + s8*16]     = c0;
    *(uint4*)&PeL[slot*136 + s8*16 + 8] = c1;
  }
  {
    size_t krow = (size_t)(b*LL + r8)*DM + (size_t)n*HD + s8*16;
    *(uint4*)&KsH[r8*136 + s8*16]     = *(const uint4*)&khp[krow];
    *(uint4*)&KsH[r8*136 + s8*16 + 8] = *(const uint4*)&khp[krow + 8];
    *(uint4*)&KsL[r8*136 + s8*16]     = *(const uint4*)&klp[krow];
    *(uint4*)&KsL[r8*136 + s8*16 + 8] = *(const uint4*)&klp[krow + 8];
#pragma unroll
    for (int i = 0; i < 4; ++i) {
      int vrow = vr0 + 8*i;
      float4 vv = *(const float4*)&qv[(size_t)(b*LL + vrow)*(2*DM) + DM + n*HD + vd4];
      float xs[4] = {vv.x, vv.y, vv.z, vv.w};
#pragma unroll
      for (int e = 0; e < 4; ++e) {
        unsigned u = __float_as_uint(xs[e]);
        VtH[(vd4+e)*40 + vrow] = (unsigned short)(u >> 16);
        VtL[(vd4+e)*40 + vrow] = f2b(xs[e] - __uint_as_float(u & 0xffff0000u));
      }
    }
  }
  __syncthreads();

  float m_run[4] = {-3.0e38f, -3.0e38f, -3.0e38f, -3.0e38f};
  float l_run[4] = {0.f, 0.f, 0.f, 0.f};
  f32x4 accO[8] = {};

  for (int kt = 0; kt < NKT; ++kt) {
    const int k0 = kt * KT;
    const int base_w = k0 - q0w + 497;

    // ---- A) prefetch tile kt+1 into registers ----
    uint4 kxh0, kxh1, kxl0, kxl1, pxh0, pxh1, pxl0, pxl1;
    float4 vx[4];
    const bool pf = kt < NKT-1;
    int pslot = 0;
    if (pf) {
      size_t krow = (size_t)(b*LL + k0 + KT + r8)*DM + (size_t)n*HD + s8*16;
      kxh0 = *(const uint4*)&khp[krow];     kxh1 = *(const uint4*)&khp[krow + 8];
      kxl0 = *(const uint4*)&klp[krow];     kxl1 = *(const uint4*)&klp[krow + 8];
      int prow = 32*kt - q0 + 545 + r8;
      int prc = prow > PEN-1 ? PEN-1 : prow;
      pslot = prow & 127;
      pxh0 = *(const uint4*)&pehp[(size_t)prc*HD + s8*16];
      pxh1 = *(const uint4*)&pehp[(size_t)prc*HD + s8*16 + 8];
      pxl0 = *(const uint4*)&pelp[(size_t)prc*HD + s8*16];
      pxl1 = *(const uint4*)&pelp[(size_t)prc*HD + s8*16 + 8];
#pragma unroll
      for (int i = 0; i < 4; ++i)
        vx[i] = *(const float4*)&qv[(size_t)(b*LL + k0 + KT + vr0 + 8*i)*(2*DM) + DM + n*HD + vd4];
    }

    // ---- B) compute tile kt ----
    float d2v[3];
#pragma unroll
    for (int jt = 0; jt < 3; ++jt)
      d2v[jt] = d2p[n*PEN + base_w + jt*16 + lm];

    // pe-term MFMA -> Bsc (+d2)
    f32x4 accB[3] = {};
#pragma unroll
    for (int jt = 0; jt < 3; ++jt) {
      const int slot = (base_w + jt*16 + lm) & 127;
#pragma unroll
      for (int c = 0; c < 4; ++c) {
        bf16x8 ph = *(const bf16x8*)&PeH[slot*136 + c*32 + lg*8];
        bf16x8 pl = *(const bf16x8*)&PeL[slot*136 + c*32 + lg*8];
        accB[jt] = __builtin_amdgcn_mfma_f32_16x16x32_bf16(qah[c], ph, accB[jt], 0, 0, 0);
        accB[jt] = __builtin_amdgcn_mfma_f32_16x16x32_bf16(qah[c], pl, accB[jt], 0, 0, 0);
        accB[jt] = __builtin_amdgcn_mfma_f32_16x16x32_bf16(qal[c], ph, accB[jt], 0, 0, 0);
      }
    }
#pragma unroll
    for (int jt = 0; jt < 3; ++jt)
#pragma unroll
      for (int r = 0; r < 4; ++r)
        Bsc[w][(lg*4 + r)*48 + jt*16 + lm] = accB[jt][r] + d2v[jt];
    asm volatile("s_waitcnt lgkmcnt(0)" ::: "memory");
    __builtin_amdgcn_sched_barrier(0);

    // AC MFMA
    f32x4 accA[2] = {};
#pragma unroll
    for (int tt = 0; tt < 2; ++tt)
#pragma unroll
      for (int c = 0; c < 4; ++c) {
        bf16x8 kfh = *(const bf16x8*)&KsH[(tt*16+lm)*136 + c*32 + lg*8];
        bf16x8 kfl = *(const bf16x8*)&KsL[(tt*16+lm)*136 + c*32 + lg*8];
        accA[tt] = __builtin_amdgcn_mfma_f32_16x16x32_bf16(qah[c], kfh, accA[tt], 0, 0, 0);
        accA[tt] = __builtin_amdgcn_mfma_f32_16x16x32_bf16(qah[c], kfl, accA[tt], 0, 0, 0);
        accA[tt] = __builtin_amdgcn_mfma_f32_16x16x32_bf16(qal[c], kfh, accA[tt], 0, 0, 0);
      }

    // softmax in C-layout (rows lg*4+r, cols lm+16t)
    float s[2][4];
#pragma unroll
    for (int tt = 0; tt < 2; ++tt)
#pragma unroll
      for (int r = 0; r < 4; ++r) {
        int qi = lg*4 + r;
        int kc = tt*16 + lm;
        int j  = kc - qi + 15;
        float v = accA[tt][r] + Bsc[w][qi*48 + j];
        s[tt][r] = (mask_s[k0 + kc] == 0) ? -1e30f : v;
      }
    float sc4[4];
#pragma unroll
    for (int r = 0; r < 4; ++r) {
      float mt = fmaxf(s[0][r], s[1][r]);
      mt = fmaxf(mt, __shfl_xor(mt, 1));
      mt = fmaxf(mt, __shfl_xor(mt, 2));
      mt = fmaxf(mt, __shfl_xor(mt, 4));
      mt = fmaxf(mt, __shfl_xor(mt, 8));
      float mn = fmaxf(m_run[r], mt);
      sc4[r] = __expf(m_run[r] - mn);
      m_run[r] = mn;
      float p0 = __expf(s[0][r] - mn);
      float p1 = __expf(s[1][r] - mn);
      s[0][r] = p0; s[1][r] = p1;
      float la = p0 + p1;
      la += __shfl_xor(la, 1);
      la += __shfl_xor(la, 2);
      la += __shfl_xor(la, 4);
      la += __shfl_xor(la, 8);
      l_run[r] = l_run[r]*sc4[r] + la;
    }
#pragma unroll
    for (int j8 = 0; j8 < 8; ++j8)
#pragma unroll
      for (int r = 0; r < 4; ++r)
        accO[j8][r] *= sc4[r];

    // P -> split bf16 in LDS (A-frag layout source)
#pragma unroll
    for (int tt = 0; tt < 2; ++tt)
#pragma unroll
      for (int r = 0; r < 4; ++r) {
        int qi = lg*4 + r, kc = tt*16 + lm;
        float p = s[tt][r];
        unsigned u = __float_as_uint(p);
        PsH[w][qi*40 + kc] = (unsigned short)(u >> 16);
        PsL[w][qi*40 + kc] = f2b(p - __uint_as_float(u & 0xffff0000u));
      }
    asm volatile("s_waitcnt lgkmcnt(0)" ::: "memory");
    __builtin_amdgcn_sched_barrier(0);

    // PV MFMA (3-pass)
    {
      bf16x8 pah = *(const bf16x8*)&PsH[w][lm*40 + lg*8];
      bf16x8 pal = *(const bf16x8*)&PsL[w][lm*40 + lg*8];
#pragma unroll
      for (int j8 = 0; j8 < 8; ++j8) {
        bf16x8 vfh = *(const bf16x8*)&VtH[(j8*16+lm)*40 + lg*8];
        bf16x8 vfl = *(const bf16x8*)&VtL[(j8*16+lm)*40 + lg*8];
        accO[j8] = __builtin_amdgcn_mfma_f32_16x16x32_bf16(pah, vfh, accO[j8], 0, 0, 0);
        accO[j8] = __builtin_amdgcn_mfma_f32_16x16x32_bf16(pah, vfl, accO[j8], 0, 0, 0);
        accO[j8] = __builtin_amdgcn_mfma_f32_16x16x32_bf16(pal, vfh, accO[j8], 0, 0, 0);
      }
    }

    __syncthreads();   // all waves done reading Ks/Vt/current pe window

    // ---- C) write staged tile kt+1 ----
    if (pf) {
      *(uint4*)&KsH[r8*136 + s8*16]     = kxh0;
      *(uint4*)&KsH[r8*136 + s8*16 + 8] = kxh1;
      *(uint4*)&KsL[r8*136 + s8*16]     = kxl0;
      *(uint4*)&KsL[r8*136 + s8*16 + 8] = kxl1;
      *(uint4*)&PeH[pslot*136 + s8*16]     = pxh0;
      *(uint4*)&PeH[pslot*136 + s8*16 + 8] = pxh1;
      *(uint4*)&PeL[pslot*136 + s8*16]     = pxl0;
      *(uint4*)&PeL[pslot*136 + s8*16 + 8] = pxl1;
#pragma unroll
      for (int i = 0; i < 4; ++i) {
        int vrow = vr0 + 8*i;
        float xs[4] = {vx[i].x, vx[i].y, vx[i].z, vx[i].w};
#pragma unroll
        for (int e = 0; e < 4; ++e) {
          unsigned u = __float_as_uint(xs[e]);
          VtH[(vd4+e)*40 + vrow] = (unsigned short)(u >> 16);
          VtL[(vd4+e)*40 + vrow] = f2b(xs[e] - __uint_as_float(u & 0xffff0000u));
        }
      }
    }
    __syncthreads();
  }

  // ---- epilogue: O / l  ->  q-half of qv ----
  float inv[4];
#pragma unroll
  for (int r = 0; r < 4; ++r) inv[r] = 1.0f / l_run[r];
#pragma unroll
  for (int j8 = 0; j8 < 8; ++j8)
#pragma unroll
    for (int r = 0; r < 4; ++r)
      outp[(size_t)(b*LL + q0w + lg*4 + r)*(2*DM) + n*HD + j8*16 + lm] = accO[j8][r] * inv[r];
}

// ------- residual add + layernorm (+ split hi/lo bf16 for next GEMM) -------
__global__ __launch_bounds__(256) void add_ln_kernel(
    const float* __restrict__ y, int ys,
    const float* __restrict__ res,
    const float* __restrict__ g, const float* __restrict__ bt,
    float* __restrict__ out,
    unsigned short* __restrict__ ohi, unsigned short* __restrict__ olo)
{
  const int r = blockIdx.x, t = threadIdx.x;
  float4 v = *(const float4*)&y[(size_t)r*ys + t*4];
  float4 w = *(const float4*)&res[(size_t)r*DM + t*4];
  float4 s = {v.x+w.x, v.y+w.y, v.z+w.z, v.w+w.w};
  float sum = s.x + s.y + s.z + s.w;
  float ssq = s.x*s.x + s.y*s.y + s.z*s.z + s.w*s.w;
#pragma unroll
  for (int off = 32; off >= 1; off >>= 1) {
    sum += __shfl_down(sum, off);
    ssq += __shfl_down(ssq, off);
  }
  __shared__ float red[8];
  int wid = t >> 6;
  if ((t & 63) == 0) { red[wid] = sum; red[wid+4] = ssq; }
  __syncthreads();
  float totS = red[0] + red[1] + red[2] + red[3];
  float totQ = red[4] + red[5] + red[6] + red[7];
  float mu  = totS * (1.0f/DM);
  float var = totQ * (1.0f/DM) - mu*mu;
  float inv = rsqrtf(var + 1e-5f);
  float4 gg = *(const float4*)&g[t*4];
  float4 bb = *(const float4*)&bt[t*4];
  float4 o;
  o.x = (s.x - mu)*inv*gg.x + bb.x;
  o.y = (s.y - mu)*inv*gg.y + bb.y;
  o.z = (s.z - mu)*inv*gg.z + bb.z;
  o.w = (s.w - mu)*inv*gg.w + bb.w;
  *(float4*)&out[(size_t)r*DM + t*4] = o;
  float xs[4] = {o.x, o.y, o.z, o.w};
  ushort4 h4, l4;
  unsigned short* hp = (unsigned short*)&h4;
  unsigned short* lp = (unsigned short*)&l4;
#pragma unroll
  for (int e = 0; e < 4; ++e) {
    unsigned short h = f2b(xs[e]);
    hp[e] = h;
    lp[e] = f2b(xs[e] - b2f(h));
  }
  *(ushort4*)&ohi[(size_t)r*DM + t*4] = h4;
  *(ushort4*)&olo[(size_t)r*DM + t*4] = l4;
}

extern "C" void kernel_launch(void* const* d_in, const int* in_sizes, int n_in,
                              void* d_out, int out_size, void* d_ws, size_t ws_size,
                              hipStream_t stream) {
  const float* x    = (const float*)d_in[0];
  const int*   mask = (const int*)d_in[1];
  const float* qv_w = (const float*)d_in[2];
  const float* rrb  = (const float*)d_in[3];
  const float* rwb  = (const float*)d_in[4];
  const float* ln1g = (const float*)d_in[5];
  const float* ln1b = (const float*)d_in[6];
  const float* ffnw = (const float*)d_in[7];
  const float* ffnb = (const float*)d_in[8];
  const float* ln2g = (const float*)d_in[9];
  const float* ln2b = (const float*)d_in[10];

  float* h  = (float*)d_out;                      // [MM][DM] hidden (f32)
  unsigned short* peh = (unsigned short*)d_ws;    // 131072 sh
  unsigned short* pel = peh + (size_t)PEN*HD;     // 131072 sh
  float* d2  = (float*)(pel + (size_t)PEN*HD);    // 8192 f32
  float* qv  = d2 + (size_t)NH*PEN;               // MM*2DM f32 (32 MB)
  unsigned short* hhi = (unsigned short*)(qv + (size_t)MM*2*DM);  // MM*DM
  unsigned short* hlo = hhi + (size_t)MM*DM;                      // MM*DM
  // total = 50,888,704 bytes

  hipMemcpyAsync(h, x, (size_t)MM*DM*sizeof(float), hipMemcpyDeviceToDevice, stream);
  split_kernel<<<(MM*DM)/1024, 256, 0, stream>>>(x, hhi, hlo, MM*DM);
  pe_kernel<<<(PEN*HD)/256, 256, 0, stream>>>(peh, pel);

  for (int l = 0; l < NL; ++l) {
    const float* rr_l = rrb + (size_t)l*NH*HD;
    const float* rw_l = rwb + (size_t)l*NH*HD;
    d2_kernel<<<(NH*PEN)/256, 256, 0, stream>>>(rr_l, rw_l, peh, pel, d2);
    // qv (f32) = h @ qv_w^T   [4096 x 2048]
    gemm_mfma<false><<<dim3((2*DM)/128, MM/128), 256, 0, stream>>>(
        hhi, hlo, qv_w + (size_t)l*2*DM*DM, nullptr, qv, 2*DM, DM, 2*DM);
    // fused relative attention -> q-half of qv
    attn_mfma<<<dim3(LL/QT, NH, BB), 256, 0, stream>>>(
        qv, hhi, hlo, peh, pel, rr_l, mask, d2, qv);
    // h = LN1(attn + h), + split
    add_ln_kernel<<<MM, 256, 0, stream>>>(qv, 2*DM, h,
        ln1g + (size_t)l*DM, ln1b + (size_t)l*DM, h, hhi, hlo);
    // ffn out (f32) = relu(h @ ffn_w^T + b) -> v-half of qv
    gemm_mfma<true><<<dim3(DM/128, MM/128), 256, 0, stream>>>(
        hhi, hlo, ffnw + (size_t)l*DM*DM, ffnb + (size_t)l*DM, qv + DM, DM, DM, 2*DM);
    // h = LN2(ffn + h), + split
    add_ln_kernel<<<MM, 256, 0, stream>>>(qv + DM, 2*DM, h,
        ln2g + (size_t)l*DM, ln2b + (size_t)l*DM, h, hhi, hlo);
  }
  (void)in_sizes; (void)n_in; (void)out_size; (void)ws_size;
}